// Round 10
// baseline (1369.029 us; speedup 1.0000x reference)
//
#include <hip/hip_runtime.h>

// WaveNet (nsynth batch-folding) on MI355X — persistent kernel, v10.
// Stream identity: batch-folding dilation == dilated conv over one 8192-sample
// stream, j = l*2 + n; fold-d taps at j +- 2d, zero-pad at stream ends.
//
// v10 = v5 (proven 970us: 8 waves, ring-3 global_load_lds weight DMA, counted
// vmcnt, register-resident H/S masters, cross-barrier prefetch) + ONE change:
// block-staggered chunk schedule. All 256 blocks used to walk the same 1MB
// weight array in lockstep after each grid barrier -> same-line L2/L3 bank
// storms. Block with in-XCD index m starts phase 1 at chunk (m%24) and
// phase 2 at K-quarter (m%8), spreading requests across banks.

#define TS 8192
#define NL 30
#define NBLK 256

typedef __attribute__((ext_vector_type(8))) short bf16x8;
typedef __attribute__((ext_vector_type(4))) float f32x4;

__device__ __forceinline__ unsigned short f2bf(float f) {
    union { float f; unsigned int u; } v; v.f = f;
    unsigned int u = v.u;
    u += 0x7fffu + ((u >> 16) & 1u);   // RNE
    return (unsigned short)(u >> 16);
}

__device__ __forceinline__ void gload_lds16(const void* g, void* l) {
    __builtin_amdgcn_global_load_lds(
        (const __attribute__((address_space(1))) void*)g,
        (__attribute__((address_space(3))) void*)l, 16, 0, 0);
}

#define VMW8()  asm volatile("s_waitcnt vmcnt(8)" ::: "memory")
#define VMW4()  asm volatile("s_waitcnt vmcnt(4)" ::: "memory")
#define VMW0()  asm volatile("s_waitcnt vmcnt(0)" ::: "memory")
#define LGKM0() asm volatile("s_waitcnt lgkmcnt(0)" ::: "memory")
#define SBAR()  __builtin_amdgcn_s_barrier()
#define MFMA16(a, b, c) __builtin_amdgcn_mfma_f32_16x16x32_bf16((a), (b), (c), 0, 0, 0)

__device__ __forceinline__ int swz_jb(int bid) {   // XCD-chunked j-tile map
    return ((bid & 7) << 5) | (bid >> 3);
}

// ---------------------------------------------------------------------------
// Weight prep: fp32 -> bf16 with layout transforms.
// Wgf[k][t][o][ci], o in [0,512): 0..255 gate, 256..511 feat (tap t split out)
// Wts[k][o][ci],    o in [0,512): 0..255 thru, 256..511 skip
// ---------------------------------------------------------------------------
__global__ void prep_weights_kernel(
    const float* __restrict__ gw, const float* __restrict__ fw,
    const float* __restrict__ tw, const float* __restrict__ sw,
    const float* __restrict__ iw, const float* __restrict__ fnw,
    unsigned short* __restrict__ Wgf, unsigned short* __restrict__ Wts,
    unsigned short* __restrict__ Wib, unsigned short* __restrict__ Wfb)
{
    const int idx = blockIdx.x * blockDim.x + threadIdx.x;
    const int stride = gridDim.x * blockDim.x;
    const int n_gf = NL * 3 * 512 * 256;
    for (int i = idx; i < n_gf; i += stride) {
        int ci = i & 255;
        int o  = (i >> 8) & 511;
        int r  = i >> 17;      // k*3 + t
        int t  = r % 3;
        int k  = r / 3;
        float v = (o < 256) ? gw[((k * 256 + o) * 256 + ci) * 3 + t]
                            : fw[((k * 256 + (o - 256)) * 256 + ci) * 3 + t];
        Wgf[i] = f2bf(v);
    }
    const int n_ts = NL * 512 * 256;
    for (int i = idx; i < n_ts; i += stride) {
        int ci = i & 255;
        int o  = (i >> 8) & 511;
        int k  = i >> 17;
        float v = (o < 256) ? tw[(k * 256 + o) * 256 + ci]
                            : sw[(k * 256 + (o - 256)) * 256 + ci];
        Wts[i] = f2bf(v);
    }
    for (int i = idx; i < 256 * 256; i += stride) Wib[i] = f2bf(iw[i]);
    for (int i = idx; i < 256 * 256; i += stride) Wfb[i] = f2bf(fnw[i]);
}

// ---------------------------------------------------------------------------
__device__ __forceinline__ void grid_barrier(unsigned* cnt, unsigned target, int tid) {
    __syncthreads();
    if (tid == 0) {
        __hip_atomic_fetch_add(cnt, 1u, __ATOMIC_RELEASE, __HIP_MEMORY_SCOPE_AGENT);
        while (__hip_atomic_load(cnt, __ATOMIC_RELAXED, __HIP_MEMORY_SCOPE_AGENT) < target)
            __builtin_amdgcn_s_sleep(2);
        (void)__hip_atomic_load(cnt, __ATOMIC_ACQUIRE, __HIP_MEMORY_SCOPE_AGENT);
    }
    __syncthreads();
}

// ---------------------------------------------------------------------------
// B-chunk staging (v5 pattern, explicit buf): chunk c in [0,32): c<24 -> Wgf
// tap t=c>>3, kc=c&7 (gate rows 32w.., feat rows 256+32w..); c>=24 -> Wts
// kc=c-24 (rows 64w..). Per-wave slice, ring-3 x 4KB. Linear LDS dest;
// 16B-slot XOR pre-swizzle on the SOURCE, undone at read (bread).
// ---------------------------------------------------------------------------
__device__ __forceinline__ void stage_chunk(
    const unsigned short* __restrict__ Wgf_k,
    const unsigned short* __restrict__ Wts_k,
    unsigned short* B_lds, int c, int buf, int w, int lane)
{
    const int rsub = lane >> 2;                       // 0..15
    const int slot = (lane & 3) ^ ((lane >> 3) & 3);  // pre-swizzled src slot
    unsigned short* dst = B_lds + w * 6144 + buf * 2048;
    if (c < 24) {
        const int t = c >> 3, kc = c & 7;
        const unsigned short* Wb = Wgf_k + (t * 512 + 32 * w) * 256 + kc * 32 + slot * 8;
        #pragma unroll
        for (int q = 0; q < 4; ++q) {
            const int r_loc = q * 16 + rsub;                   // 0..63
            const int grow  = (q < 2) ? r_loc : (224 + r_loc); // feat at +256
            gload_lds16(Wb + grow * 256, dst + q * 512);
        }
    } else {
        const int kc = c - 24;
        const unsigned short* Wb = Wts_k + (64 * w) * 256 + kc * 32 + slot * 8;
        #pragma unroll
        for (int q = 0; q < 4; ++q)
            gload_lds16(Wb + (q * 16 + rsub) * 256, dst + q * 512);
    }
}

// read B fragment: local row r (0..63), k-quarter krow (0..3)
__device__ __forceinline__ bf16x8 bread(const unsigned short* Bw, int r, int krow)
{
    const int slot = krow ^ ((r >> 1) & 3);
    return *(const bf16x8*)(Bw + r * 32 + slot * 8);
}

// ---------------------------------------------------------------------------
__global__ __launch_bounds__(512, 2)
void wavenet_kernel(const float* __restrict__ x,
                    const float* __restrict__ init_w,
                    const float* __restrict__ init_b,
                    const unsigned short* __restrict__ Wib,
                    const float* __restrict__ ib,
                    const unsigned short* __restrict__ Wgf,
                    const unsigned short* __restrict__ Wts,
                    const float* __restrict__ gbA,
                    const float* __restrict__ fbA,
                    const unsigned short* __restrict__ Wfb,
                    const float* __restrict__ fbias,
                    unsigned short* __restrict__ Hb0,
                    unsigned short* __restrict__ Hb1,
                    float* __restrict__ out,
                    unsigned* __restrict__ counter)
{
    __shared__ __align__(16) unsigned short A_lds[3 * 32 * 256];   // 48 KB
    __shared__ __align__(16) unsigned short B_lds[8 * 3 * 2048];   // 96 KB

    const int tid  = threadIdx.x;
    const int lane = tid & 63;
    const int w    = tid >> 6;
    const int j0   = swz_jb(blockIdx.x) * 32;
    const int arow = lane & 15;
    const int krow = lane >> 4;
    const int aswz = (arow & 7) << 4;
    const int cg0  = w * 32;
    const int c0   = w * 64;          // H cols (w<4) base
    const int cs0  = (w - 4) * 64;    // S cols (w>=4) base

    // block-stagger offsets (in-XCD index m = bid>>3 spreads L2 bank traffic)
    const int m_in_xcd = blockIdx.x >> 3;
    const int off1 = m_in_xcd % 24;   // phase-1 start chunk
    const int off2 = m_in_xcd % 8;    // phase-2 start K-quarter

    // persistent fp32 masters
    f32x4 state[2][4];

    // ================= init conv -> state (waves 0-3), Hb0 + LDS tap1 ======
    if (w < 4) {
        #pragma unroll
        for (int rt = 0; rt < 2; ++rt)
            #pragma unroll
            for (int fc = 0; fc < 4; ++fc) {
                #pragma unroll
                for (int i = 0; i < 4; ++i) {
                    const int row = rt * 16 + krow * 4 + i;
                    const int col = c0 + fc * 16 + arow;
                    const int j   = j0 + row;
                    float acc = init_b[col];
                    #pragma unroll
                    for (int t = 0; t < 3; ++t) {
                        const int i2 = j + 2 * t - 2;
                        if (i2 >= 0 && i2 < TS)
                            acc += init_w[col * 3 + t] * x[(i2 & 1) * 4096 + (i2 >> 1)];
                    }
                    state[rt][fc][i] = acc;
                    const unsigned short hb = f2bf(acc);
                    Hb0[(j << 8) + col] = hb;
                    A_lds[((32 + row) << 8) + (((col << 1) ^ ((row & 7) << 4)) >> 1)] = hb;
                }
            }
    }
    LGKM0(); SBAR();   // H0 (bf16) visible in tap1

    // ================= iskip -> state (waves 4-7) ==========================
    if (w >= 4) {
        #pragma unroll
        for (int rt = 0; rt < 2; ++rt)
            #pragma unroll
            for (int fc = 0; fc < 4; ++fc) {
                const float b = ib[cs0 + fc * 16 + arow];
                state[rt][fc] = (f32x4){b, b, b, b};
            }
        #pragma unroll
        for (int kc = 0; kc < 8; ++kc) {
            const int aoff = ((kc * 64 + krow * 16) ^ aswz) >> 1;
            const bf16x8 a0 = *(const bf16x8*)(A_lds + ((32 + arow) << 8) + aoff);
            const bf16x8 a1 = *(const bf16x8*)(A_lds + ((48 + arow) << 8) + aoff);
            const int koff = kc * 32 + krow * 8;
            #pragma unroll
            for (int fc = 0; fc < 4; ++fc) {
                const bf16x8 bb = *(const bf16x8*)(Wib + ((cs0 + fc * 16 + arow) << 8) + koff);
                state[0][fc] = MFMA16(a0, bb, state[0][fc]);
                state[1][fc] = MFMA16(a1, bb, state[1][fc]);
            }
        }
    }

    // pre-stage layer-0 steps 0,1 (= chunks off1, off1+1), fly across barrier
    stage_chunk(Wgf, Wts, B_lds, off1, 0, w, lane);
    stage_chunk(Wgf, Wts, B_lds, (off1 + 1) % 24, 1, w, lane);

    unsigned target = NBLK;
    grid_barrier(counter, target, tid);

    const unsigned short* Hb_in = Hb0;
    unsigned short*       Hb_out = Hb1;

    // ============================ layer loop ================================
    for (int k = 0; k < NL; ++k) {
        const int d = 2 << (k % 10);   // stream dilation = 2 * 2^(k%10)
        const unsigned short* Wgf_k = Wgf + (size_t)k * 393216;
        const unsigned short* Wts_k = Wts + (size_t)k * 131072;

        const float* Pbase = (w < 4) ? (const float*)0 : (const float*)0; (void)Pbase;

        // ---- A-stage: taps 0 and 2 only (center tap already in tap1) ----
        #pragma unroll
        for (int q = 0; q < 4; ++q) {
            const int cc  = tid + q * 512;
            const int c16 = cc & 31;
            const int m   = (cc >> 5) & 31;
            const int t   = (cc >> 10) << 1;            // 0 or 2
            const int r   = j0 + m + (t - 1) * d;
            uint4 v = make_uint4(0u, 0u, 0u, 0u);
            if (r >= 0 && r < TS)
                v = *(const uint4*)(Hb_in + (r << 8) + (c16 << 3));
            const int sb = (c16 << 4) ^ ((m & 7) << 4);
            *(uint4*)(A_lds + ((t * 32 + m) << 8) + (sb >> 1)) = v;
        }
        LGKM0(); SBAR();   // A complete (steps 0,1 DMA already landed)

        // ---- phase 1: 24 steps, staggered chunk ids, ring-3, vmcnt(8) ----
        const float gv0 = gbA[k * 256 + cg0 + arow];
        const float gv1 = gbA[k * 256 + cg0 + 16 + arow];
        const float fv0 = fbA[k * 256 + cg0 + arow];
        const float fv1 = fbA[k * 256 + cg0 + 16 + arow];
        f32x4 accG[2][2], accF[2][2];
        accG[0][0] = (f32x4){gv0, gv0, gv0, gv0}; accG[1][0] = accG[0][0];
        accG[0][1] = (f32x4){gv1, gv1, gv1, gv1}; accG[1][1] = accG[0][1];
        accF[0][0] = (f32x4){fv0, fv0, fv0, fv0}; accF[1][0] = accF[0][0];
        accF[0][1] = (f32x4){fv1, fv1, fv1, fv1}; accF[1][1] = accF[0][1];

        #pragma unroll
        for (int i = 0; i < 24; ++i) {
            // stage the chunk consumed at step i+2
            const int cnext = (i <= 21) ? ((i + 2 + off1) % 24)
                                        : (24 + (i - 22 + off2) % 8);
            stage_chunk(Wgf_k, Wts_k, B_lds, cnext, (i + 2) % 3, w, lane);
            VMW8();                                     // step-i chunk landed
            const int c = (i + off1) % 24;              // this step's chunk id
            const int t = c >> 3, kc = c & 7;
            const int aoff = ((kc * 64 + krow * 16) ^ aswz) >> 1;
            const unsigned short* At = A_lds + ((t * 32 + arow) << 8);
            const bf16x8 a0 = *(const bf16x8*)(At + aoff);
            const bf16x8 a1 = *(const bf16x8*)(At + (16 << 8) + aoff);
            const unsigned short* Bw = B_lds + w * 6144 + (i % 3) * 2048;
            const bf16x8 bg0 = bread(Bw, arow, krow);
            const bf16x8 bg1 = bread(Bw, 16 + arow, krow);
            const bf16x8 bf0 = bread(Bw, 32 + arow, krow);
            const bf16x8 bf1 = bread(Bw, 48 + arow, krow);
            accG[0][0] = MFMA16(a0, bg0, accG[0][0]);
            accG[1][0] = MFMA16(a1, bg0, accG[1][0]);
            accG[0][1] = MFMA16(a0, bg1, accG[0][1]);
            accG[1][1] = MFMA16(a1, bg1, accG[1][1]);
            accF[0][0] = MFMA16(a0, bf0, accF[0][0]);
            accF[1][0] = MFMA16(a1, bf0, accF[1][0]);
            accF[0][1] = MFMA16(a0, bf1, accF[0][1]);
            accF[1][1] = MFMA16(a1, bf1, accF[1][1]);
        }

        LGKM0(); SBAR();   // phase-1 LDS reads done (tap0 reused for res)

        // ---- res = sigmoid(G)*tanh(F) -> tap0 (swizzled) ----
        #pragma unroll
        for (int rt = 0; rt < 2; ++rt)
            #pragma unroll
            for (int fc = 0; fc < 2; ++fc)
                #pragma unroll
                for (int i = 0; i < 4; ++i) {
                    const float g = accG[rt][fc][i];
                    const float f = accF[rt][fc][i];
                    const float sg = 1.0f / (1.0f + __expf(-g));
                    const float e2 = __expf(2.0f * f);
                    const float th = 1.0f - 2.0f / (e2 + 1.0f);
                    const float rr = sg * th;
                    const int row = rt * 16 + krow * 4 + i;
                    const int col = cg0 + fc * 16 + arow;
                    A_lds[(row << 8) + (((col << 1) ^ ((row & 7) << 4)) >> 1)] = f2bf(rr);
                }
        LGKM0(); SBAR();   // res visible (steps 24,25 chunks in flight)

        // ---- phase 2: 8 steps, staggered K-quarters; acc from state ----
        f32x4 acc2[2][4];
        #pragma unroll
        for (int rt = 0; rt < 2; ++rt)
            #pragma unroll
            for (int fc = 0; fc < 4; ++fc)
                acc2[rt][fc] = state[rt][fc];

        #pragma unroll
        for (int p = 0; p < 8; ++p) {
            if (p < 6) {
                stage_chunk(Wgf_k, Wts_k, B_lds, 24 + (p + 2 + off2) % 8,
                            (24 + p + 2) % 3, w, lane);
                VMW8();
            }
            else if (p == 6) { VMW4(); }
            else             { VMW0(); }
            const int kq = (p + off2) % 8;              // K-quarter this step
            const int aoff = ((kq * 64 + krow * 16) ^ aswz) >> 1;
            const bf16x8 a0 = *(const bf16x8*)(A_lds + (arow << 8) + aoff);
            const bf16x8 a1 = *(const bf16x8*)(A_lds + ((16 + arow) << 8) + aoff);
            const unsigned short* Bw = B_lds + w * 6144 + ((24 + p) % 3) * 2048;
            const bf16x8 b0 = bread(Bw, arow, krow);
            const bf16x8 b1 = bread(Bw, 16 + arow, krow);
            const bf16x8 b2 = bread(Bw, 32 + arow, krow);
            const bf16x8 b3 = bread(Bw, 48 + arow, krow);
            acc2[0][0] = MFMA16(a0, b0, acc2[0][0]);
            acc2[1][0] = MFMA16(a1, b0, acc2[1][0]);
            acc2[0][1] = MFMA16(a0, b1, acc2[0][1]);
            acc2[1][1] = MFMA16(a1, b1, acc2[1][1]);
            acc2[0][2] = MFMA16(a0, b2, acc2[0][2]);
            acc2[1][2] = MFMA16(a1, b2, acc2[1][2]);
            acc2[0][3] = MFMA16(a0, b3, acc2[0][3]);
            acc2[1][3] = MFMA16(a1, b3, acc2[1][3]);
        }

        // ---- state update (registers only) ----
        #pragma unroll
        for (int rt = 0; rt < 2; ++rt)
            #pragma unroll
            for (int fc = 0; fc < 4; ++fc)
                state[rt][fc] = acc2[rt][fc];

        if (k < NL - 1) {
            // prefetch next layer's steps 0,1 into bufs 0,1 (read at p=6,7;
            // loop is done) — DMA flies under epilogue + barrier wait.
            stage_chunk(Wgf_k + 393216, Wts_k + 131072, B_lds, off1, 0, w, lane);
            stage_chunk(Wgf_k + 393216, Wts_k + 131072, B_lds, (off1 + 1) % 24, 1, w, lane);

            // waves 0-3: publish bf16 H to global (halo) + LDS tap1 (center)
            if (w < 4) {
                #pragma unroll
                for (int rt = 0; rt < 2; ++rt)
                    #pragma unroll
                    for (int fc = 0; fc < 4; ++fc)
                        #pragma unroll
                        for (int i = 0; i < 4; ++i) {
                            const int row = rt * 16 + krow * 4 + i;
                            const int col = c0 + fc * 16 + arow;
                            const unsigned short hb = f2bf(state[rt][fc][i]);
                            Hb_out[((j0 + row) << 8) + col] = hb;
                            A_lds[((32 + row) << 8) + (((col << 1) ^ ((row & 7) << 4)) >> 1)] = hb;
                        }
            }
            target += NBLK;
            grid_barrier(counter, target, tid);   // drains prefetch + publishes H

            unsigned short* tmp = (unsigned short*)Hb_in;
            Hb_in = Hb_out; Hb_out = tmp;
        } else {
            // last layer: S (waves 4-7) -> tap0 bf16 for the final GEMM
            LGKM0(); SBAR();   // all phase-2 tap0 reads done
            if (w >= 4) {
                #pragma unroll
                for (int rt = 0; rt < 2; ++rt)
                    #pragma unroll
                    for (int fc = 0; fc < 4; ++fc)
                        #pragma unroll
                        for (int i = 0; i < 4; ++i) {
                            const int row = rt * 16 + krow * 4 + i;
                            const int col = cs0 + fc * 16 + arow;
                            A_lds[(row << 8) + (((col << 1) ^ ((row & 7) << 4)) >> 1)] =
                                f2bf(state[rt][fc][i]);
                        }
            }
            LGKM0(); SBAR();
        }
    }

    // ================= final: out = Wfb @ S^T + fbias =======================
    {
        const int m0 = w * 32;   // co slice
        f32x4 facc[2][2];
        #pragma unroll
        for (int rt = 0; rt < 2; ++rt)
            #pragma unroll
            for (int fc = 0; fc < 2; ++fc)
                facc[rt][fc] = (f32x4){0.f, 0.f, 0.f, 0.f};

        #pragma unroll
        for (int kc = 0; kc < 8; ++kc) {
            const int koff = kc * 32 + krow * 8;
            const bf16x8 a0 = *(const bf16x8*)(Wfb + ((m0 + arow) << 8) + koff);
            const bf16x8 a1 = *(const bf16x8*)(Wfb + ((m0 + 16 + arow) << 8) + koff);
            const int aoff = ((kc * 64 + krow * 16) ^ aswz) >> 1;
            const bf16x8 b0 = *(const bf16x8*)(A_lds + (arow << 8) + aoff);
            const bf16x8 b1 = *(const bf16x8*)(A_lds + ((16 + arow) << 8) + aoff);
            facc[0][0] = MFMA16(a0, b0, facc[0][0]);
            facc[1][0] = MFMA16(a1, b0, facc[1][0]);
            facc[0][1] = MFMA16(a0, b1, facc[0][1]);
            facc[1][1] = MFMA16(a1, b1, facc[1][1]);
        }

        #pragma unroll
        for (int rt = 0; rt < 2; ++rt)
            #pragma unroll
            for (int fc = 0; fc < 2; ++fc)
                #pragma unroll
                for (int i = 0; i < 4; ++i) {
                    const int co = m0 + rt * 16 + krow * 4 + i;
                    const int jj = j0 + fc * 16 + arow;
                    out[((jj & 1) << 20) + (co << 12) + (jj >> 1)] = facc[rt][fc][i] + fbias[co];
                }
    }
}

// ---------------------------------------------------------------------------
extern "C" void kernel_launch(void* const* d_in, const int* in_sizes, int n_in,
                              void* d_out, int out_size, void* d_ws, size_t ws_size,
                              hipStream_t stream)
{
    const float* x       = (const float*)d_in[0];
    const float* init_w  = (const float*)d_in[1];
    const float* init_b  = (const float*)d_in[2];
    const float* iskip_w = (const float*)d_in[3];
    const float* iskip_b = (const float*)d_in[4];
    const float* gate_w  = (const float*)d_in[5];
    const float* gate_b  = (const float*)d_in[6];
    const float* feat_w  = (const float*)d_in[7];
    const float* feat_b  = (const float*)d_in[8];
    const float* skip_w  = (const float*)d_in[9];
    const float* thru_w  = (const float*)d_in[10];
    const float* final_w = (const float*)d_in[11];
    const float* final_b = (const float*)d_in[12];

    char* ws = (char*)d_ws;
    size_t off = 0;
    auto alloc = [&](size_t bytes) {
        void* p = ws + off;
        off += (bytes + 255) & ~(size_t)255;
        return p;
    };
    unsigned short* Wgf = (unsigned short*)alloc((size_t)NL * 3 * 512 * 256 * 2);
    unsigned short* Wts = (unsigned short*)alloc((size_t)NL * 512 * 256 * 2);
    unsigned short* Wib = (unsigned short*)alloc(256 * 256 * 2);
    unsigned short* Wfb = (unsigned short*)alloc(256 * 256 * 2);
    unsigned short* Hb0 = (unsigned short*)alloc((size_t)TS * 256 * 2);
    unsigned short* Hb1 = (unsigned short*)alloc((size_t)TS * 256 * 2);
    unsigned*       cnt = (unsigned*)alloc(256);

    hipMemsetAsync((void*)cnt, 0, 256, stream);
    prep_weights_kernel<<<2048, 256, 0, stream>>>(gate_w, feat_w, thru_w, skip_w,
                                                  iskip_w, final_w, Wgf, Wts, Wib, Wfb);
    wavenet_kernel<<<NBLK, 512, 0, stream>>>(
        x, init_w, init_b, Wib, iskip_b, Wgf, Wts, gate_b, feat_b,
        Wfb, final_b, Hb0, Hb1, (float*)d_out, cnt);
}